// Round 13
// baseline (287.644 us; speedup 1.0000x reference)
//
#include <hip/hip_runtime.h>
#include <hip/hip_bf16.h>

#define NROW 8192
#define NDIM 256
#define INV_T (1.0f / 0.07f)
#define K_BOT 819      // first selected descending rank
#define K_TOP 4095     // one past last selected rank
#define N_SEL 3276
#define N_UNSEL 4916   // 8192 - N_SEL (includes diagonal at -10)

typedef unsigned int u32;
typedef unsigned short u16;
typedef short s16;
typedef unsigned long long u64;
typedef __bf16 bf16_t;
typedef s16 s16x8 __attribute__((ext_vector_type(8)));
typedef float f32x4 __attribute__((ext_vector_type(4)));

__device__ __forceinline__ u16 bfbits(float f) {
    return __builtin_bit_cast(u16, (bf16_t)f);   // RNE f32->bf16, raw bits
}
// order-preserving bf16-bits -> u16 key (bigger float <=> bigger key)
__device__ __forceinline__ u16 map16(u16 b) {
    return (b & 0x8000u) ? (u16)~b : (u16)(b | 0x8000u);
}
__device__ __forceinline__ float unmap16(u32 m) {
    u16 b = (m & 0x8000u) ? (u16)(m & 0x7FFFu) : (u16)~(u16)m;
    return __uint_as_float(((u32)b) << 16);
}

__device__ __forceinline__ void gload16(const void* g, void* l) {
    __builtin_amdgcn_global_load_lds(
        (const __attribute__((address_space(1))) u32*)g,
        (__attribute__((address_space(3))) u32*)l, 16, 0, 0);
}

// ---------------- fp32 -> bf16 (both inputs, one launch) ----------------
__global__ __launch_bounds__(256) void cvt_bf16(const float* __restrict__ in0,
                                                const float* __restrict__ in1,
                                                u16* __restrict__ out0,
                                                u16* __restrict__ out1) {
    int b = blockIdx.x;
    const float* in = (b < 2048) ? in0 : in1;
    u16* out = (b < 2048) ? out0 : out1;
    int i = ((b & 2047) * 256 + threadIdx.x) * 4;
    float4 v = *(const float4*)(in + i);
    ushort4 o;
    o.x = bfbits(v.x); o.y = bfbits(v.y); o.z = bfbits(v.z); o.w = bfbits(v.w);
    *(ushort4*)(out + i) = o;
}

// ---------------- GEMM: keys = map16(bf16(Q @ K^T)) ----------------
// 128x128 tile, BK=32 (8 K-steps), 4 waves (2x2). LDS halved vs round-12:
// staging 8+8 KB; epilogue transposes in TWO row-half passes through a
// [64][132] sC aliasing the staging => LDS block 16896 B => 6 blocks/CU
// (VGPR-limited), vs 4 before. Diagonal sentinel folded into sC write.
__global__ __launch_bounds__(256, 6) void gemm_keys(const u16* __restrict__ Qb,
                                                    const u16* __restrict__ Kb,
                                                    u16* __restrict__ Cp) {
    constexpr int BK = 32;
    __shared__ __align__(16) char smem[64 * 132 * 2];   // 16896 B (union)
    u16* sA = (u16*)smem;                    // [128][32] bf16 (8 KB)
    u16* sB = (u16*)(smem + 8192);           // [128][32] (8 KB)
    u16* sC = (u16*)smem;                    // [64][132] epilogue transpose

    const int tid  = threadIdx.x;
    const int lane = tid & 63;
    const int wid  = tid >> 6;
    const int wr = wid >> 1, wc = wid & 1;
    const int bm = blockIdx.y * 128;
    const int bn = blockIdx.x * 128;
    const int kg = lane >> 4;                // chunk 0..3 (8 bf16 = 16 B)
    const int fr = lane & 15;

    // staging: segment = 16 rows x 64 B; lane l -> row seg*16 + (l>>2),
    // LDS slot s = l&3 holds source chunk j = s ^ ((row>>1)&3) = (l&3)^((l>>3)&3)
    const int srr = lane >> 2;
    const int srj = (lane & 3) ^ ((lane >> 3) & 3);

    f32x4 acc[4][4] = {};

    for (int k0 = 0; k0 < NDIM; k0 += BK) {
        __syncthreads();
#pragma unroll
        for (int s = 0; s < 2; ++s) {
            int seg = wid * 2 + s;                // 0..7 (16 rows each)
            int row = seg * 16 + srr;
            gload16(Qb + (size_t)(bm + row) * NDIM + k0 + srj * 8, &sA[seg * 512]);
            gload16(Kb + (size_t)(bn + row) * NDIM + k0 + srj * 8, &sB[seg * 512]);
        }
        __syncthreads();

        s16x8 af[4], bfv[4];
        const int jp = kg ^ ((fr >> 1) & 3);
#pragma unroll
        for (int m = 0; m < 4; ++m) {
            int row = wr * 64 + m * 16 + fr;
            af[m] = *(const s16x8*)(&sA[row * BK + jp * 8]);
        }
#pragma unroll
        for (int n = 0; n < 4; ++n) {
            int row = wc * 64 + n * 16 + fr;
            bfv[n] = *(const s16x8*)(&sB[row * BK + jp * 8]);
        }
#pragma unroll
        for (int m = 0; m < 4; ++m)
#pragma unroll
            for (int n = 0; n < 4; ++n)
                acc[m][n] = __builtin_amdgcn_mfma_f32_16x16x32_bf16(
                    af[m], bfv[n], acc[m][n], 0, 0, 0);
    }

    // epilogue: two row-half passes through [64][132] sC (aliases staging)
    const bool diagTile = (bm == bn);
#pragma unroll
    for (int p = 0; p < 2; ++p) {
        __syncthreads();                 // staging/sC free for this pass
        if (wr == p) {
#pragma unroll
            for (int m = 0; m < 4; ++m)
#pragma unroll
                for (int n = 0; n < 4; ++n)
#pragma unroll
                    for (int jj = 0; jj < 4; ++jj) {
                        int rl = m * 16 + kg * 4 + jj;    // local row 0..63
                        int c  = wc * 64 + n * 16 + fr;
                        bool dz = diagTile && (wc == p) && (n == m) &&
                                  (fr == kg * 4 + jj);    // diagonal sentinel
                        u16 key = map16(bfbits(acc[m][n][jj]));
                        sC[rl * 132 + c] = dz ? (u16)0 : key;
                    }
        }
        __syncthreads();
#pragma unroll
        for (int it = 0; it < 4; ++it) {
            int idx = it * 256 + tid;              // 0..1023 16B chunks
            int rl = idx >> 4, col8 = (idx & 15) * 8;
            *(uint4*)(&Cp[(size_t)(bm + p * 64 + rl) * NROW + bn + col8]) =
                *(const uint4*)(&sC[rl * 132 + col8]);
        }
    }
}

// ---------------- rank select + LSE: 1 wave/row, 0 barriers, 2 sweeps -----
// resolve rank `rem` within a 128-key sub-hist (packed u16 counts, 64 words)
__device__ __forceinline__ void resolve_slot(const u32* sub, int slot, u32 rem,
                                             int lane, u32* idxOut, u32* gtOut) {
    u32 word = sub[slot * 64 + lane];
    u32 c0 = word & 0xFFFFu, c1 = word >> 16;     // idx 2*lane, 2*lane+1
    u32 s0 = c0 + c1, suf = s0;
#pragma unroll
    for (int o = 1; o < 64; o <<= 1) {
        u32 v = __shfl_down(suf, o);
        if (lane + o < 64) suf += v;
    }
    u32 TexL = suf - s0;                  // counts in higher lanes
    u32 f = 0, pk = 0;
    u32 ab0 = TexL + c1;                  // keys above idx 2*lane
    if (rem >= ab0 && rem < ab0 + c0) { f = 1; pk = ((u32)(lane * 2) << 16) | ab0; }
    if (rem >= TexL && rem < TexL + c1) { f = 1; pk = ((u32)(lane * 2 + 1) << 16) | TexL; }
    u64 mm = __ballot(f != 0);
    pk = __shfl(pk, (int)(__ffsll((unsigned long long)mm) - 1));
    *idxOut = pk >> 16;
    *gtOut = pk & 0xFFFFu;
}

__global__ __launch_bounds__(256, 8) void rank_lse(const u16* __restrict__ Cp,
                                                   const float* __restrict__ fq,
                                                   const float* __restrict__ fk,
                                                   float* __restrict__ loss) {
    __shared__ u32 lds_s[4][1152];        // 18.4 KB total; per-wave private
    const int t = threadIdx.x;
    const int w = t >> 6;
    const int lane = t & 63;
    const int row = blockIdx.x * 4 + w;

    u32* W  = lds_s[w];
    u32* h1 = W;                           // [0,512)    S1 hist copy 0
    u32* h2 = W + 520;                     // [520,1032) S1 hist copy 1 (bank-offset)
    u32* sub = W;                          // [0,512)    phase-2 sub-hists (alias h1)

    const uint4* rp = (const uint4*)(Cp + (size_t)row * NROW);

    // zero hist copies
    {
        const uint4 z = make_uint4(0, 0, 0, 0);
#pragma unroll
        for (int i = 0; i < 4; ++i) *(uint4*)&W[i * 256 + lane * 4] = z;
        *(uint2*)&W[1024 + lane * 2] = make_uint2(0, 0);
    }

    // exact fp32 l_pos
    float lp;
    {
        float4 q4 = *(const float4*)(fq + (size_t)row * NDIM + lane * 4);
        float4 k4 = *(const float4*)(fk + (size_t)row * NDIM + lane * 4);
        float p = q4.x * k4.x + q4.y * k4.y + q4.z * k4.z + q4.w * k4.w;
#pragma unroll
        for (int o = 32; o; o >>= 1) p += __shfl_down(p, o);
        lp = __shfl(p, 0);
    }

    // ---- S1: 512-bin hist (key>>7), 2-copy split by lane parity ----
    u32* const hb = (lane & 1) ? h2 : h1;
#pragma unroll 4
    for (int i = 0; i < 16; ++i) {
        uint4 v = rp[i * 64 + lane];
        u32 vv[4] = { v.x, v.y, v.z, v.w };
#pragma unroll
        for (int q = 0; q < 4; ++q) {
            atomicAdd(&hb[(vv[q] >> 7) & 0x1FFu], 1u);
            atomicAdd(&hb[vv[q] >> 23], 1u);
        }
    }

    // ---- suffix scan (8 bins/lane over 512); locate boundary bins ----
    u32 h[8], Wa[8];
    {
        uint4 a0 = *(const uint4*)&h1[lane * 8];
        uint4 a1 = *(const uint4*)&h1[lane * 8 + 4];
        uint4 b0 = *(const uint4*)&h2[lane * 8];
        uint4 b1 = *(const uint4*)&h2[lane * 8 + 4];
        h[0] = a0.x + b0.x; h[1] = a0.y + b0.y; h[2] = a0.z + b0.z; h[3] = a0.w + b0.w;
        h[4] = a1.x + b1.x; h[5] = a1.y + b1.y; h[6] = a1.z + b1.z; h[7] = a1.w + b1.w;
    }
    Wa[7] = 0;
#pragma unroll
    for (int j = 6; j >= 0; --j) Wa[j] = Wa[j + 1] + h[j + 1];
    u32 P = Wa[0] + h[0];
    u32 s = P;
#pragma unroll
    for (int o = 1; o < 64; o <<= 1) {
        u32 vv = __shfl_down(s, o);
        if (lane + o < 64) s += vv;
    }
    const u32 Tex = s - P;

    u32 fA = 0, pkA = 0, fB = 0, pkB = 0;
#pragma unroll
    for (int j = 0; j < 8; ++j) {
        u32 T = Tex + Wa[j];
        u32 e = T + h[j];
        if ((u32)K_BOT >= T && (u32)K_BOT < e)
            { fA = 1; pkA = ((u32)(lane * 8 + j) << 13) | ((u32)K_BOT - T); }
        if ((u32)(K_TOP - 1) >= T && (u32)(K_TOP - 1) < e)
            { fB = 1; pkB = ((u32)(lane * 8 + j) << 13) | ((u32)(K_TOP - 1) - T); }
    }
    {
        u64 mA = __ballot(fA != 0);
        pkA = __shfl(pkA, (int)(__ffsll((unsigned long long)mA) - 1));
        u64 mB = __ballot(fB != 0);
        pkB = __shfl(pkB, (int)(__ffsll((unsigned long long)mB) - 1));
    }
    const u32 binA = pkA >> 13, remA = pkA & 8191u;
    const u32 binB = pkB >> 13, remB = pkB & 8191u;
    const u32 TA = (u32)K_BOT - remA;
    const u32 TB = (u32)(K_TOP - 1) - remB;

    // ---- slot assignment (pure arithmetic) ----
    const float edgeA = unmap16(binA << 7);
    int lo2, topSlots;
    bool fb = false;
    if (edgeA > -1e37f && edgeA < 1e37f) {
        float vt = edgeA - 2.8f;
        int vtBin = (int)((u32)map16(bfbits(vt)) >> 7);
        int binLoSafe = vtBin - 1; if (binLoSafe < 0) binLoSafe = 0;
        int m = (binLoSafe < (int)binA) ? binLoSafe : (int)binA;
        lo2 = ((int)binB + 1 > m) ? (int)binB + 1 : m;
        topSlots = ((int)binA >= lo2) ? ((int)binA - lo2 + 1) : 0;
        if (topSlots + 1 > 8) fb = true;
    } else {
        fb = true;
    }
    if (fb) {                       // fallback: slots only for binB, binA
        lo2 = (int)binA;
        topSlots = ((int)binA > (int)binB) ? 1 : 0;
    }
    const int nslot = topSlots + 1;
    const int sA = topSlots;        // slot of binA (0 when binA==binB)

    // ---- zero sub region, then S2: sub-hist sweep (packed u16 counts) ----
    {
        const uint4 z = make_uint4(0, 0, 0, 0);
#pragma unroll
        for (int i = 0; i < 2; ++i) *(uint4*)&sub[i * 256 + lane * 4] = z;
    }
#pragma unroll 4
    for (int i = 0; i < 16; ++i) {
        uint4 v = rp[i * 64 + lane];
        u32 vv[4] = { v.x, v.y, v.z, v.w };
#pragma unroll
        for (int q = 0; q < 4; ++q) {
#pragma unroll
            for (int hh = 0; hh < 2; ++hh) {
                u32 key = hh ? (vv[q] >> 16) : (vv[q] & 0xFFFFu);
                u32 b = key >> 7;
                int sl = (b == binB) ? 0
                       : (((u32)((int)b - lo2) < (u32)topSlots) ? ((int)b - lo2 + 1) : -1);
                if (sl >= 0)
                    atomicAdd(&sub[sl * 64 + ((key & 127u) >> 1)],
                              (key & 1u) ? 0x10000u : 1u);
            }
        }
    }

    // ---- resolve exact boundary keys + tie counts ----
    u32 idxA, gtA, idxB, gtB;
    resolve_slot(sub, sA, remA, lane, &idxA, &gtA);
    resolve_slot(sub, 0,  remB, lane, &idxB, &gtB);
    const u32 ua = (binA << 7) | idxA;
    const u32 ub = (binB << 7) | idxB;
    const u32 Ga = TA + gtA;
    const u32 Gb = TB + gtB;
    u32 Ea;
    {
        u32 wv = sub[sA * 64 + (idxA >> 1)];
        Ea = (idxA & 1u) ? (wv >> 16) : (wv & 0xFFFFu);
    }

    const float a  = unmap16(ua);
    const float m_ = fmaxf(fmaxf(lp, a), -10.0f) * INV_T;   // exact max

    // ---- window sum ----
    float sm = 0.f;
    if (!fb) {
        for (int ss = 0; ss < nslot; ++ss) {          // wave-uniform
            u32 bs = (ss == 0) ? binB : (u32)(lo2 + ss - 1);
            u32 wv = sub[ss * 64 + lane];
            u32 c0 = wv & 0xFFFFu, c1 = wv >> 16;
            u32 k0 = (bs << 7) | (u32)(lane * 2);
            u32 k1 = k0 | 1u;
            if (c0 && k0 > ub && k0 < ua)
                sm += (float)c0 * __expf(unmap16(k0) * INV_T - m_);
            if (c1 && k1 > ub && k1 < ua)
                sm += (float)c1 * __expf(unmap16(k1) * INV_T - m_);
        }
    } else if (ua != ub) {
        // rare fallback: one extra full sweep with exact m_
        const u32 lo1 = ub + 1u, span = ua - ub - 1u;
#pragma unroll 4
        for (int i = 0; i < 16; ++i) {
            uint4 v = rp[i * 64 + lane];
            u32 vv[4] = { v.x, v.y, v.z, v.w };
#pragma unroll
            for (int q = 0; q < 4; ++q) {
#pragma unroll
                for (int hh = 0; hh < 2; ++hh) {
                    u32 key = hh ? (vv[q] >> 16) : (vv[q] & 0xFFFFu);
                    bool in = (key - lo1) < span;
                    float e = __expf(unmap16(key) * INV_T - m_);
                    sm += in ? e : 0.f;
                }
            }
        }
    }
#pragma unroll
    for (int o = 32; o; o >>= 1) sm += __shfl_down(sm, o);

    if (lane == 0) {
        float bv = unmap16(ub);
        float expA = __expf(a * INV_T - m_);
        float tot;
        if (ua == ub) {
            tot = (float)N_SEL * expA;
        } else {
            float expB = __expf(bv * INV_T - m_);
            tot = sm + (float)(int)(Ga + Ea - (u32)K_BOT) * expA
                     + (float)(int)((u32)K_TOP - Gb) * expB;
        }
        tot += __expf(lp * INV_T - m_) + (float)N_UNSEL * __expf(-10.0f * INV_T - m_);
        loss[row] = m_ + __logf(tot) - lp * INV_T;
    }
}

// ---------------- host ----------------
extern "C" void kernel_launch(void* const* d_in, const int* in_sizes, int n_in,
                              void* d_out, int out_size, void* d_ws, size_t ws_size,
                              hipStream_t stream) {
    const float* fq = (const float*)d_in[0];
    const float* fk = (const float*)d_in[1];
    float* out = (float*)d_out;

    char* ws = (char*)d_ws;
    u16* keys = (u16*)ws;                                  // 128 MiB
    u16* qb = (u16*)(ws + (size_t)NROW * NROW * 2);        // 4 MiB
    u16* kb = qb + (size_t)NROW * NDIM;                    // 4 MiB

    cvt_bf16<<<4096, 256, 0, stream>>>(fq, fk, qb, kb);
    gemm_keys<<<dim3(NROW / 128, NROW / 128), 256, 0, stream>>>(qb, kb, keys);
    rank_lse<<<NROW / 4, 256, 0, stream>>>(keys, fq, fk, out);
}

// Round 14
// 122.942 us; speedup vs baseline: 2.3397x; 2.3397x over previous
//
#include <hip/hip_runtime.h>
#include <hip/hip_bf16.h>

#define NROW 8192
#define NDIM 256
#define INV_T (1.0f / 0.07f)
#define K_BOT 819      // first selected descending rank
#define K_TOP 4095     // one past last selected rank
#define N_SEL 3276
#define N_UNSEL 4916   // 8192 - N_SEL (includes diagonal at -10)

typedef unsigned int u32;
typedef unsigned short u16;
typedef short s16;
typedef unsigned long long u64;
typedef __bf16 bf16_t;
typedef s16 s16x8 __attribute__((ext_vector_type(8)));
typedef float f32x4 __attribute__((ext_vector_type(4)));

__device__ __forceinline__ u16 bfbits(float f) {
    return __builtin_bit_cast(u16, (bf16_t)f);   // RNE f32->bf16, raw bits
}
// order-preserving bf16-bits -> u16 key (bigger float <=> bigger key)
__device__ __forceinline__ u16 map16(u16 b) {
    return (b & 0x8000u) ? (u16)~b : (u16)(b | 0x8000u);
}
__device__ __forceinline__ float unmap16(u32 m) {
    u16 b = (m & 0x8000u) ? (u16)(m & 0x7FFFu) : (u16)~(u16)m;
    return __uint_as_float(((u32)b) << 16);
}

__device__ __forceinline__ void gload16(const void* g, void* l) {
    __builtin_amdgcn_global_load_lds(
        (const __attribute__((address_space(1))) u32*)g,
        (__attribute__((address_space(3))) u32*)l, 16, 0, 0);
}

// ---------------- fp32 -> bf16 (both inputs, one launch) ----------------
__global__ __launch_bounds__(256) void cvt_bf16(const float* __restrict__ in0,
                                                const float* __restrict__ in1,
                                                u16* __restrict__ out0,
                                                u16* __restrict__ out1) {
    int b = blockIdx.x;
    const float* in = (b < 2048) ? in0 : in1;
    u16* out = (b < 2048) ? out0 : out1;
    int i = ((b & 2047) * 256 + threadIdx.x) * 4;
    float4 v = *(const float4*)(in + i);
    ushort4 o;
    o.x = bfbits(v.x); o.y = bfbits(v.y); o.z = bfbits(v.z); o.w = bfbits(v.w);
    *(ushort4*)(out + i) = o;
}

// ---------------- GEMM: keys = map16(bf16(Q @ K^T)) ----------------
// 128x128 tile, BK=64, **8 waves (512 thr)**, wave tile 64x32 -> acc only
// 32 regs/wave (vs 64 at 4 waves). No min-waves launch_bounds (round-13
// lesson: unified VGPR/AGPR file + forced cap => scratch spill, 3.5x slower).
// Staging layout/swizzle identical to the proven round-12 kernel.
__global__ __launch_bounds__(512) void gemm_keys(const u16* __restrict__ Qb,
                                                 const u16* __restrict__ Kb,
                                                 u16* __restrict__ Cp) {
    constexpr int BK = 64;
    __shared__ __align__(16) char smem[128 * 132 * 2];   // 33792 B (union)
    u16* sA = (u16*)smem;                    // [128][64] bf16 (16 KB)
    u16* sB = (u16*)(smem + 128 * BK * 2);   // [128][64] (16 KB)
    u16* sC = (u16*)smem;                    // [128][132] epilogue transpose

    const int tid  = threadIdx.x;
    const int lane = tid & 63;
    const int wid  = tid >> 6;               // 0..7
    const int wr = wid & 1;                  // row half   (64 rows)
    const int wc = wid >> 1;                 // col quarter (32 cols)
    const int bm = blockIdx.y * 128;
    const int bn = blockIdx.x * 128;
    const int kg = lane >> 4;
    const int fr = lane & 15;

    // staging: segment = 8 rows x 128B; lane l -> row seg*8 + (l>>3),
    // LDS chunk jp = l&7 holds source chunk j = jp ^ (row&7).
    const int srr = lane >> 3;
    const int srj = (lane & 7) ^ srr;

    f32x4 acc[4][2] = {};

    for (int k0 = 0; k0 < NDIM; k0 += BK) {
        __syncthreads();
#pragma unroll
        for (int s = 0; s < 2; ++s) {
            int seg = wid * 2 + s;               // 0..15
            int row = seg * 8 + srr;
            gload16(Qb + (size_t)(bm + row) * NDIM + k0 + srj * 8, &sA[seg * 512]);
            gload16(Kb + (size_t)(bn + row) * NDIM + k0 + srj * 8, &sB[seg * 512]);
        }
        __syncthreads();

#pragma unroll
        for (int kk = 0; kk < 2; ++kk) {
            s16x8 af[4], bfv[2];
            const int jp = (kk * 4 + kg) ^ (fr & 7);   // row&7 == fr&7 below
#pragma unroll
            for (int m = 0; m < 4; ++m) {
                int row = wr * 64 + m * 16 + fr;
                af[m] = *(const s16x8*)(&sA[row * BK + jp * 8]);
            }
#pragma unroll
            for (int n = 0; n < 2; ++n) {
                int row = wc * 32 + n * 16 + fr;
                bfv[n] = *(const s16x8*)(&sB[row * BK + jp * 8]);
            }
#pragma unroll
            for (int m = 0; m < 4; ++m)
#pragma unroll
                for (int n = 0; n < 2; ++n)
                    acc[m][n] = __builtin_amdgcn_mfma_f32_16x16x32_bf16(
                        af[m], bfv[n], acc[m][n], 0, 0, 0);
        }
    }

    __syncthreads();   // done reading sA/sB; reuse LDS as sC
#pragma unroll
    for (int m = 0; m < 4; ++m)
#pragma unroll
        for (int n = 0; n < 2; ++n)
#pragma unroll
            for (int jj = 0; jj < 4; ++jj) {
                int r = wr * 64 + m * 16 + kg * 4 + jj;   // C/D: row=(lane>>4)*4+reg
                int c = wc * 32 + n * 16 + fr;            //      col=lane&15
                sC[r * 132 + c] = map16(bfbits(acc[m][n][jj]));
            }
    __syncthreads();
    if (bm == bn) {
        if (tid < 128) sC[tid * 132 + tid] = 0;   // diagonal sentinel (unique min)
        __syncthreads();
    }
#pragma unroll
    for (int it = 0; it < 4; ++it) {
        int idx = it * 512 + tid;                 // 0..2047 16B chunks
        int row = idx >> 4, col8 = (idx & 15) * 8;
        *(uint4*)(&Cp[(size_t)(bm + row) * NROW + bn + col8]) =
            *(const uint4*)(&sC[row * 132 + col8]);
    }
}

// ---------------- rank select + LSE: 1 wave/row, 0 barriers, 2 sweeps -----
// resolve rank `rem` within a 128-key sub-hist (packed u16 counts, 64 words)
__device__ __forceinline__ void resolve_slot(const u32* sub, int slot, u32 rem,
                                             int lane, u32* idxOut, u32* gtOut) {
    u32 word = sub[slot * 64 + lane];
    u32 c0 = word & 0xFFFFu, c1 = word >> 16;     // idx 2*lane, 2*lane+1
    u32 s0 = c0 + c1, suf = s0;
#pragma unroll
    for (int o = 1; o < 64; o <<= 1) {
        u32 v = __shfl_down(suf, o);
        if (lane + o < 64) suf += v;
    }
    u32 TexL = suf - s0;                  // counts in higher lanes
    u32 f = 0, pk = 0;
    u32 ab0 = TexL + c1;                  // keys above idx 2*lane
    if (rem >= ab0 && rem < ab0 + c0) { f = 1; pk = ((u32)(lane * 2) << 16) | ab0; }
    if (rem >= TexL && rem < TexL + c1) { f = 1; pk = ((u32)(lane * 2 + 1) << 16) | TexL; }
    u64 mm = __ballot(f != 0);
    pk = __shfl(pk, (int)(__ffsll((unsigned long long)mm) - 1));
    *idxOut = pk >> 16;
    *gtOut = pk & 0xFFFFu;
}

__global__ __launch_bounds__(256, 8) void rank_lse(const u16* __restrict__ Cp,
                                                   const float* __restrict__ fq,
                                                   const float* __restrict__ fk,
                                                   float* __restrict__ loss) {
    __shared__ u32 lds_s[4][1152];        // 18.4 KB total; per-wave private
    const int t = threadIdx.x;
    const int w = t >> 6;
    const int lane = t & 63;
    const int row = blockIdx.x * 4 + w;

    u32* W  = lds_s[w];
    u32* h1 = W;                           // [0,512)    S1 hist copy 0
    u32* h2 = W + 520;                     // [520,1032) S1 hist copy 1 (bank-offset)
    u32* sub = W;                          // [0,512)    phase-2 sub-hists (alias h1)

    const uint4* rp = (const uint4*)(Cp + (size_t)row * NROW);

    // zero hist copies
    {
        const uint4 z = make_uint4(0, 0, 0, 0);
#pragma unroll
        for (int i = 0; i < 4; ++i) *(uint4*)&W[i * 256 + lane * 4] = z;
        *(uint2*)&W[1024 + lane * 2] = make_uint2(0, 0);
    }

    // exact fp32 l_pos
    float lp;
    {
        float4 q4 = *(const float4*)(fq + (size_t)row * NDIM + lane * 4);
        float4 k4 = *(const float4*)(fk + (size_t)row * NDIM + lane * 4);
        float p = q4.x * k4.x + q4.y * k4.y + q4.z * k4.z + q4.w * k4.w;
#pragma unroll
        for (int o = 32; o; o >>= 1) p += __shfl_down(p, o);
        lp = __shfl(p, 0);
    }

    // ---- S1: 512-bin hist (key>>7), 2-copy split by lane parity ----
    u32* const hb = (lane & 1) ? h2 : h1;
#pragma unroll 4
    for (int i = 0; i < 16; ++i) {
        uint4 v = rp[i * 64 + lane];
        u32 vv[4] = { v.x, v.y, v.z, v.w };
#pragma unroll
        for (int q = 0; q < 4; ++q) {
            atomicAdd(&hb[(vv[q] >> 7) & 0x1FFu], 1u);
            atomicAdd(&hb[vv[q] >> 23], 1u);
        }
    }

    // ---- suffix scan (8 bins/lane over 512); locate boundary bins ----
    u32 h[8], Wa[8];
    {
        uint4 a0 = *(const uint4*)&h1[lane * 8];
        uint4 a1 = *(const uint4*)&h1[lane * 8 + 4];
        uint4 b0 = *(const uint4*)&h2[lane * 8];
        uint4 b1 = *(const uint4*)&h2[lane * 8 + 4];
        h[0] = a0.x + b0.x; h[1] = a0.y + b0.y; h[2] = a0.z + b0.z; h[3] = a0.w + b0.w;
        h[4] = a1.x + b1.x; h[5] = a1.y + b1.y; h[6] = a1.z + b1.z; h[7] = a1.w + b1.w;
    }
    Wa[7] = 0;
#pragma unroll
    for (int j = 6; j >= 0; --j) Wa[j] = Wa[j + 1] + h[j + 1];
    u32 P = Wa[0] + h[0];
    u32 s = P;
#pragma unroll
    for (int o = 1; o < 64; o <<= 1) {
        u32 vv = __shfl_down(s, o);
        if (lane + o < 64) s += vv;
    }
    const u32 Tex = s - P;

    u32 fA = 0, pkA = 0, fB = 0, pkB = 0;
#pragma unroll
    for (int j = 0; j < 8; ++j) {
        u32 T = Tex + Wa[j];
        u32 e = T + h[j];
        if ((u32)K_BOT >= T && (u32)K_BOT < e)
            { fA = 1; pkA = ((u32)(lane * 8 + j) << 13) | ((u32)K_BOT - T); }
        if ((u32)(K_TOP - 1) >= T && (u32)(K_TOP - 1) < e)
            { fB = 1; pkB = ((u32)(lane * 8 + j) << 13) | ((u32)(K_TOP - 1) - T); }
    }
    {
        u64 mA = __ballot(fA != 0);
        pkA = __shfl(pkA, (int)(__ffsll((unsigned long long)mA) - 1));
        u64 mB = __ballot(fB != 0);
        pkB = __shfl(pkB, (int)(__ffsll((unsigned long long)mB) - 1));
    }
    const u32 binA = pkA >> 13, remA = pkA & 8191u;
    const u32 binB = pkB >> 13, remB = pkB & 8191u;
    const u32 TA = (u32)K_BOT - remA;
    const u32 TB = (u32)(K_TOP - 1) - remB;

    // ---- slot assignment (pure arithmetic) ----
    const float edgeA = unmap16(binA << 7);
    int lo2, topSlots;
    bool fb = false;
    if (edgeA > -1e37f && edgeA < 1e37f) {
        float vt = edgeA - 2.8f;
        int vtBin = (int)((u32)map16(bfbits(vt)) >> 7);
        int binLoSafe = vtBin - 1; if (binLoSafe < 0) binLoSafe = 0;
        int m = (binLoSafe < (int)binA) ? binLoSafe : (int)binA;
        lo2 = ((int)binB + 1 > m) ? (int)binB + 1 : m;
        topSlots = ((int)binA >= lo2) ? ((int)binA - lo2 + 1) : 0;
        if (topSlots + 1 > 8) fb = true;
    } else {
        fb = true;
    }
    if (fb) {                       // fallback: slots only for binB, binA
        lo2 = (int)binA;
        topSlots = ((int)binA > (int)binB) ? 1 : 0;
    }
    const int nslot = topSlots + 1;
    const int sA = topSlots;        // slot of binA (0 when binA==binB)

    // ---- zero sub region, then S2: sub-hist sweep (packed u16 counts) ----
    {
        const uint4 z = make_uint4(0, 0, 0, 0);
#pragma unroll
        for (int i = 0; i < 2; ++i) *(uint4*)&sub[i * 256 + lane * 4] = z;
    }
#pragma unroll 4
    for (int i = 0; i < 16; ++i) {
        uint4 v = rp[i * 64 + lane];
        u32 vv[4] = { v.x, v.y, v.z, v.w };
#pragma unroll
        for (int q = 0; q < 4; ++q) {
#pragma unroll
            for (int hh = 0; hh < 2; ++hh) {
                u32 key = hh ? (vv[q] >> 16) : (vv[q] & 0xFFFFu);
                u32 b = key >> 7;
                int sl = (b == binB) ? 0
                       : (((u32)((int)b - lo2) < (u32)topSlots) ? ((int)b - lo2 + 1) : -1);
                if (sl >= 0)
                    atomicAdd(&sub[sl * 64 + ((key & 127u) >> 1)],
                              (key & 1u) ? 0x10000u : 1u);
            }
        }
    }

    // ---- resolve exact boundary keys + tie counts ----
    u32 idxA, gtA, idxB, gtB;
    resolve_slot(sub, sA, remA, lane, &idxA, &gtA);
    resolve_slot(sub, 0,  remB, lane, &idxB, &gtB);
    const u32 ua = (binA << 7) | idxA;
    const u32 ub = (binB << 7) | idxB;
    const u32 Ga = TA + gtA;
    const u32 Gb = TB + gtB;
    u32 Ea;
    {
        u32 wv = sub[sA * 64 + (idxA >> 1)];
        Ea = (idxA & 1u) ? (wv >> 16) : (wv & 0xFFFFu);
    }

    const float a  = unmap16(ua);
    const float m_ = fmaxf(fmaxf(lp, a), -10.0f) * INV_T;   // exact max

    // ---- window sum ----
    float sm = 0.f;
    if (!fb) {
        for (int ss = 0; ss < nslot; ++ss) {          // wave-uniform
            u32 bs = (ss == 0) ? binB : (u32)(lo2 + ss - 1);
            u32 wv = sub[ss * 64 + lane];
            u32 c0 = wv & 0xFFFFu, c1 = wv >> 16;
            u32 k0 = (bs << 7) | (u32)(lane * 2);
            u32 k1 = k0 | 1u;
            if (c0 && k0 > ub && k0 < ua)
                sm += (float)c0 * __expf(unmap16(k0) * INV_T - m_);
            if (c1 && k1 > ub && k1 < ua)
                sm += (float)c1 * __expf(unmap16(k1) * INV_T - m_);
        }
    } else if (ua != ub) {
        // rare fallback: one extra full sweep with exact m_
        const u32 lo1 = ub + 1u, span = ua - ub - 1u;
#pragma unroll 4
        for (int i = 0; i < 16; ++i) {
            uint4 v = rp[i * 64 + lane];
            u32 vv[4] = { v.x, v.y, v.z, v.w };
#pragma unroll
            for (int q = 0; q < 4; ++q) {
#pragma unroll
                for (int hh = 0; hh < 2; ++hh) {
                    u32 key = hh ? (vv[q] >> 16) : (vv[q] & 0xFFFFu);
                    bool in = (key - lo1) < span;
                    float e = __expf(unmap16(key) * INV_T - m_);
                    sm += in ? e : 0.f;
                }
            }
        }
    }
#pragma unroll
    for (int o = 32; o; o >>= 1) sm += __shfl_down(sm, o);

    if (lane == 0) {
        float bv = unmap16(ub);
        float expA = __expf(a * INV_T - m_);
        float tot;
        if (ua == ub) {
            tot = (float)N_SEL * expA;
        } else {
            float expB = __expf(bv * INV_T - m_);
            tot = sm + (float)(int)(Ga + Ea - (u32)K_BOT) * expA
                     + (float)(int)((u32)K_TOP - Gb) * expB;
        }
        tot += __expf(lp * INV_T - m_) + (float)N_UNSEL * __expf(-10.0f * INV_T - m_);
        loss[row] = m_ + __logf(tot) - lp * INV_T;
    }
}

// ---------------- host ----------------
extern "C" void kernel_launch(void* const* d_in, const int* in_sizes, int n_in,
                              void* d_out, int out_size, void* d_ws, size_t ws_size,
                              hipStream_t stream) {
    const float* fq = (const float*)d_in[0];
    const float* fk = (const float*)d_in[1];
    float* out = (float*)d_out;

    char* ws = (char*)d_ws;
    u16* keys = (u16*)ws;                                  // 128 MiB
    u16* qb = (u16*)(ws + (size_t)NROW * NROW * 2);        // 4 MiB
    u16* kb = qb + (size_t)NROW * NDIM;                    // 4 MiB

    cvt_bf16<<<4096, 256, 0, stream>>>(fq, fk, qb, kb);
    gemm_keys<<<dim3(NROW / 128, NROW / 128), 512, 0, stream>>>(qb, kb, keys);
    rank_lse<<<NROW / 4, 256, 0, stream>>>(keys, fq, fk, out);
}

// Round 15
// 122.692 us; speedup vs baseline: 2.3444x; 1.0020x over previous
//
#include <hip/hip_runtime.h>
#include <hip/hip_bf16.h>

#define NROW 8192
#define NDIM 256
#define INV_T (1.0f / 0.07f)
#define K_BOT 819      // first selected descending rank
#define K_TOP 4095     // one past last selected rank
#define N_SEL 3276
#define N_UNSEL 4916   // 8192 - N_SEL (includes diagonal at -10)

typedef unsigned int u32;
typedef unsigned short u16;
typedef short s16;
typedef unsigned long long u64;
typedef __bf16 bf16_t;
typedef s16 s16x8 __attribute__((ext_vector_type(8)));
typedef float f32x4 __attribute__((ext_vector_type(4)));

__device__ __forceinline__ u16 bfbits(float f) {
    return __builtin_bit_cast(u16, (bf16_t)f);   // RNE f32->bf16, raw bits
}
// order-preserving bf16-bits -> u16 key (bigger float <=> bigger key)
__device__ __forceinline__ u16 map16(u16 b) {
    return (b & 0x8000u) ? (u16)~b : (u16)(b | 0x8000u);
}
__device__ __forceinline__ float unmap16(u32 m) {
    u16 b = (m & 0x8000u) ? (u16)(m & 0x7FFFu) : (u16)~(u16)m;
    return __uint_as_float(((u32)b) << 16);
}

__device__ __forceinline__ void gload16(const void* g, void* l) {
    __builtin_amdgcn_global_load_lds(
        (const __attribute__((address_space(1))) u32*)g,
        (__attribute__((address_space(3))) u32*)l, 16, 0, 0);
}

// ---------------- fp32 -> bf16 (both inputs, one launch) ----------------
__global__ __launch_bounds__(256) void cvt_bf16(const float* __restrict__ in0,
                                                const float* __restrict__ in1,
                                                u16* __restrict__ out0,
                                                u16* __restrict__ out1) {
    int b = blockIdx.x;
    const float* in = (b < 2048) ? in0 : in1;
    u16* out = (b < 2048) ? out0 : out1;
    int i = ((b & 2047) * 256 + threadIdx.x) * 4;
    float4 v = *(const float4*)(in + i);
    ushort4 o;
    o.x = bfbits(v.x); o.y = bfbits(v.y); o.z = bfbits(v.z); o.w = bfbits(v.w);
    *(ushort4*)(out + i) = o;
}

// ---------------- GEMM: keys = map16(bf16(Q @ K^T)) ----------------
// 128x128 tile, BK=64, 8 waves (512 thr), wave tile 64x32 (acc 32 regs).
// Proven round-14 form. No min-waves launch_bounds (round-13 spill lesson).
__global__ __launch_bounds__(512) void gemm_keys(const u16* __restrict__ Qb,
                                                 const u16* __restrict__ Kb,
                                                 u16* __restrict__ Cp) {
    constexpr int BK = 64;
    __shared__ __align__(16) char smem[128 * 132 * 2];   // 33792 B (union)
    u16* sA = (u16*)smem;                    // [128][64] bf16 (16 KB)
    u16* sB = (u16*)(smem + 128 * BK * 2);   // [128][64] (16 KB)
    u16* sC = (u16*)smem;                    // [128][132] epilogue transpose

    const int tid  = threadIdx.x;
    const int lane = tid & 63;
    const int wid  = tid >> 6;               // 0..7
    const int wr = wid & 1;                  // row half   (64 rows)
    const int wc = wid >> 1;                 // col quarter (32 cols)
    const int bm = blockIdx.y * 128;
    const int bn = blockIdx.x * 128;
    const int kg = lane >> 4;
    const int fr = lane & 15;

    // staging: segment = 8 rows x 128B; lane l -> row seg*8 + (l>>3),
    // LDS chunk jp = l&7 holds source chunk j = jp ^ (row&7).
    const int srr = lane >> 3;
    const int srj = (lane & 7) ^ srr;

    f32x4 acc[4][2] = {};

    for (int k0 = 0; k0 < NDIM; k0 += BK) {
        __syncthreads();
#pragma unroll
        for (int s = 0; s < 2; ++s) {
            int seg = wid * 2 + s;               // 0..15
            int row = seg * 8 + srr;
            gload16(Qb + (size_t)(bm + row) * NDIM + k0 + srj * 8, &sA[seg * 512]);
            gload16(Kb + (size_t)(bn + row) * NDIM + k0 + srj * 8, &sB[seg * 512]);
        }
        __syncthreads();

#pragma unroll
        for (int kk = 0; kk < 2; ++kk) {
            s16x8 af[4], bfv[2];
            const int jp = (kk * 4 + kg) ^ (fr & 7);   // row&7 == fr&7 below
#pragma unroll
            for (int m = 0; m < 4; ++m) {
                int row = wr * 64 + m * 16 + fr;
                af[m] = *(const s16x8*)(&sA[row * BK + jp * 8]);
            }
#pragma unroll
            for (int n = 0; n < 2; ++n) {
                int row = wc * 32 + n * 16 + fr;
                bfv[n] = *(const s16x8*)(&sB[row * BK + jp * 8]);
            }
#pragma unroll
            for (int m = 0; m < 4; ++m)
#pragma unroll
                for (int n = 0; n < 2; ++n)
                    acc[m][n] = __builtin_amdgcn_mfma_f32_16x16x32_bf16(
                        af[m], bfv[n], acc[m][n], 0, 0, 0);
        }
    }

    __syncthreads();   // done reading sA/sB; reuse LDS as sC
#pragma unroll
    for (int m = 0; m < 4; ++m)
#pragma unroll
        for (int n = 0; n < 2; ++n)
#pragma unroll
            for (int jj = 0; jj < 4; ++jj) {
                int r = wr * 64 + m * 16 + kg * 4 + jj;   // C/D: row=(lane>>4)*4+reg
                int c = wc * 32 + n * 16 + fr;            //      col=lane&15
                sC[r * 132 + c] = map16(bfbits(acc[m][n][jj]));
            }
    __syncthreads();
    if (bm == bn) {
        if (tid < 128) sC[tid * 132 + tid] = 0;   // diagonal sentinel (unique min)
        __syncthreads();
    }
#pragma unroll
    for (int it = 0; it < 4; ++it) {
        int idx = it * 512 + tid;                 // 0..2047 16B chunks
        int row = idx >> 4, col8 = (idx & 15) * 8;
        *(uint4*)(&Cp[(size_t)(bm + row) * NROW + bn + col8]) =
            *(const uint4*)(&sC[row * 132 + col8]);
    }
}

// ---------------- rank select + LSE: 1 wave/row, 0 barriers, 2 sweeps -----
// resolve rank `rem` within a 128-key sub-hist (packed u16 counts, 64 words)
__device__ __forceinline__ void resolve_slot(const u32* sub, int slot, u32 rem,
                                             int lane, u32* idxOut, u32* gtOut) {
    u32 word = sub[slot * 64 + lane];
    u32 c0 = word & 0xFFFFu, c1 = word >> 16;     // idx 2*lane, 2*lane+1
    u32 s0 = c0 + c1, suf = s0;
#pragma unroll
    for (int o = 1; o < 64; o <<= 1) {
        u32 v = __shfl_down(suf, o);
        if (lane + o < 64) suf += v;
    }
    u32 TexL = suf - s0;                  // counts in higher lanes
    u32 f = 0, pk = 0;
    u32 ab0 = TexL + c1;                  // keys above idx 2*lane
    if (rem >= ab0 && rem < ab0 + c0) { f = 1; pk = ((u32)(lane * 2) << 16) | ab0; }
    if (rem >= TexL && rem < TexL + c1) { f = 1; pk = ((u32)(lane * 2 + 1) << 16) | TexL; }
    u64 mm = __ballot(f != 0);
    pk = __shfl(pk, (int)(__ffsll((unsigned long long)mm) - 1));
    *idxOut = pk >> 16;
    *gtOut = pk & 0xFFFFu;
}

// 128-thread blocks (2 independent waves) => 16 blocks/CU = 32 waves/CU
// (round-14: 4-wave blocks measured only 66% occupancy; waves share nothing)
__global__ __launch_bounds__(128, 8) void rank_lse(const u16* __restrict__ Cp,
                                                   const float* __restrict__ fq,
                                                   const float* __restrict__ fk,
                                                   float* __restrict__ loss) {
    __shared__ u32 lds_s[2][1152];        // 9216 B/block; per-wave private
    const int t = threadIdx.x;
    const int w = t >> 6;
    const int lane = t & 63;
    const int row = blockIdx.x * 2 + w;

    u32* W  = lds_s[w];
    u32* h1 = W;                           // [0,512)    S1 hist copy 0
    u32* h2 = W + 520;                     // [520,1032) S1 hist copy 1 (bank-offset)
    u32* sub = W;                          // [0,512)    phase-2 sub-hists (alias h1)

    const uint4* rp = (const uint4*)(Cp + (size_t)row * NROW);

    // zero hist copies
    {
        const uint4 z = make_uint4(0, 0, 0, 0);
#pragma unroll
        for (int i = 0; i < 4; ++i) *(uint4*)&W[i * 256 + lane * 4] = z;
        *(uint2*)&W[1024 + lane * 2] = make_uint2(0, 0);
    }

    // exact fp32 l_pos
    float lp;
    {
        float4 q4 = *(const float4*)(fq + (size_t)row * NDIM + lane * 4);
        float4 k4 = *(const float4*)(fk + (size_t)row * NDIM + lane * 4);
        float p = q4.x * k4.x + q4.y * k4.y + q4.z * k4.z + q4.w * k4.w;
#pragma unroll
        for (int o = 32; o; o >>= 1) p += __shfl_down(p, o);
        lp = __shfl(p, 0);
    }

    // ---- S1: 512-bin hist (key>>7), 2-copy split by lane parity ----
    u32* const hb = (lane & 1) ? h2 : h1;
#pragma unroll 4
    for (int i = 0; i < 16; ++i) {
        uint4 v = rp[i * 64 + lane];
        u32 vv[4] = { v.x, v.y, v.z, v.w };
#pragma unroll
        for (int q = 0; q < 4; ++q) {
            atomicAdd(&hb[(vv[q] >> 7) & 0x1FFu], 1u);
            atomicAdd(&hb[vv[q] >> 23], 1u);
        }
    }

    // ---- suffix scan (8 bins/lane over 512); locate boundary bins ----
    u32 h[8], Wa[8];
    {
        uint4 a0 = *(const uint4*)&h1[lane * 8];
        uint4 a1 = *(const uint4*)&h1[lane * 8 + 4];
        uint4 b0 = *(const uint4*)&h2[lane * 8];
        uint4 b1 = *(const uint4*)&h2[lane * 8 + 4];
        h[0] = a0.x + b0.x; h[1] = a0.y + b0.y; h[2] = a0.z + b0.z; h[3] = a0.w + b0.w;
        h[4] = a1.x + b1.x; h[5] = a1.y + b1.y; h[6] = a1.z + b1.z; h[7] = a1.w + b1.w;
    }
    Wa[7] = 0;
#pragma unroll
    for (int j = 6; j >= 0; --j) Wa[j] = Wa[j + 1] + h[j + 1];
    u32 P = Wa[0] + h[0];
    u32 s = P;
#pragma unroll
    for (int o = 1; o < 64; o <<= 1) {
        u32 vv = __shfl_down(s, o);
        if (lane + o < 64) s += vv;
    }
    const u32 Tex = s - P;

    u32 fA = 0, pkA = 0, fB = 0, pkB = 0;
#pragma unroll
    for (int j = 0; j < 8; ++j) {
        u32 T = Tex + Wa[j];
        u32 e = T + h[j];
        if ((u32)K_BOT >= T && (u32)K_BOT < e)
            { fA = 1; pkA = ((u32)(lane * 8 + j) << 13) | ((u32)K_BOT - T); }
        if ((u32)(K_TOP - 1) >= T && (u32)(K_TOP - 1) < e)
            { fB = 1; pkB = ((u32)(lane * 8 + j) << 13) | ((u32)(K_TOP - 1) - T); }
    }
    {
        u64 mA = __ballot(fA != 0);
        pkA = __shfl(pkA, (int)(__ffsll((unsigned long long)mA) - 1));
        u64 mB = __ballot(fB != 0);
        pkB = __shfl(pkB, (int)(__ffsll((unsigned long long)mB) - 1));
    }
    const u32 binA = pkA >> 13, remA = pkA & 8191u;
    const u32 binB = pkB >> 13, remB = pkB & 8191u;
    const u32 TA = (u32)K_BOT - remA;
    const u32 TB = (u32)(K_TOP - 1) - remB;

    // ---- slot assignment (pure arithmetic) ----
    const float edgeA = unmap16(binA << 7);
    int lo2, topSlots;
    bool fb = false;
    if (edgeA > -1e37f && edgeA < 1e37f) {
        float vt = edgeA - 2.8f;
        int vtBin = (int)((u32)map16(bfbits(vt)) >> 7);
        int binLoSafe = vtBin - 1; if (binLoSafe < 0) binLoSafe = 0;
        int m = (binLoSafe < (int)binA) ? binLoSafe : (int)binA;
        lo2 = ((int)binB + 1 > m) ? (int)binB + 1 : m;
        topSlots = ((int)binA >= lo2) ? ((int)binA - lo2 + 1) : 0;
        if (topSlots + 1 > 8) fb = true;
    } else {
        fb = true;
    }
    if (fb) {                       // fallback: slots only for binB, binA
        lo2 = (int)binA;
        topSlots = ((int)binA > (int)binB) ? 1 : 0;
    }
    const int nslot = topSlots + 1;
    const int sA = topSlots;        // slot of binA (0 when binA==binB)

    // ---- zero sub region, then S2: sub-hist sweep (packed u16 counts) ----
    {
        const uint4 z = make_uint4(0, 0, 0, 0);
#pragma unroll
        for (int i = 0; i < 2; ++i) *(uint4*)&sub[i * 256 + lane * 4] = z;
    }
#pragma unroll 4
    for (int i = 0; i < 16; ++i) {
        uint4 v = rp[i * 64 + lane];
        u32 vv[4] = { v.x, v.y, v.z, v.w };
#pragma unroll
        for (int q = 0; q < 4; ++q) {
#pragma unroll
            for (int hh = 0; hh < 2; ++hh) {
                u32 key = hh ? (vv[q] >> 16) : (vv[q] & 0xFFFFu);
                u32 b = key >> 7;
                int sl = (b == binB) ? 0
                       : (((u32)((int)b - lo2) < (u32)topSlots) ? ((int)b - lo2 + 1) : -1);
                if (sl >= 0)
                    atomicAdd(&sub[sl * 64 + ((key & 127u) >> 1)],
                              (key & 1u) ? 0x10000u : 1u);
            }
        }
    }

    // ---- resolve exact boundary keys + tie counts ----
    u32 idxA, gtA, idxB, gtB;
    resolve_slot(sub, sA, remA, lane, &idxA, &gtA);
    resolve_slot(sub, 0,  remB, lane, &idxB, &gtB);
    const u32 ua = (binA << 7) | idxA;
    const u32 ub = (binB << 7) | idxB;
    const u32 Ga = TA + gtA;
    const u32 Gb = TB + gtB;
    u32 Ea;
    {
        u32 wv = sub[sA * 64 + (idxA >> 1)];
        Ea = (idxA & 1u) ? (wv >> 16) : (wv & 0xFFFFu);
    }

    const float a  = unmap16(ua);
    const float m_ = fmaxf(fmaxf(lp, a), -10.0f) * INV_T;   // exact max

    // ---- window sum ----
    float sm = 0.f;
    if (!fb) {
        for (int ss = 0; ss < nslot; ++ss) {          // wave-uniform
            u32 bs = (ss == 0) ? binB : (u32)(lo2 + ss - 1);
            u32 wv = sub[ss * 64 + lane];
            u32 c0 = wv & 0xFFFFu, c1 = wv >> 16;
            u32 k0 = (bs << 7) | (u32)(lane * 2);
            u32 k1 = k0 | 1u;
            if (c0 && k0 > ub && k0 < ua)
                sm += (float)c0 * __expf(unmap16(k0) * INV_T - m_);
            if (c1 && k1 > ub && k1 < ua)
                sm += (float)c1 * __expf(unmap16(k1) * INV_T - m_);
        }
    } else if (ua != ub) {
        // rare fallback: one extra full sweep with exact m_
        const u32 lo1 = ub + 1u, span = ua - ub - 1u;
#pragma unroll 4
        for (int i = 0; i < 16; ++i) {
            uint4 v = rp[i * 64 + lane];
            u32 vv[4] = { v.x, v.y, v.z, v.w };
#pragma unroll
            for (int q = 0; q < 4; ++q) {
#pragma unroll
                for (int hh = 0; hh < 2; ++hh) {
                    u32 key = hh ? (vv[q] >> 16) : (vv[q] & 0xFFFFu);
                    bool in = (key - lo1) < span;
                    float e = __expf(unmap16(key) * INV_T - m_);
                    sm += in ? e : 0.f;
                }
            }
        }
    }
#pragma unroll
    for (int o = 32; o; o >>= 1) sm += __shfl_down(sm, o);

    if (lane == 0) {
        float bv = unmap16(ub);
        float expA = __expf(a * INV_T - m_);
        float tot;
        if (ua == ub) {
            tot = (float)N_SEL * expA;
        } else {
            float expB = __expf(bv * INV_T - m_);
            tot = sm + (float)(int)(Ga + Ea - (u32)K_BOT) * expA
                     + (float)(int)((u32)K_TOP - Gb) * expB;
        }
        tot += __expf(lp * INV_T - m_) + (float)N_UNSEL * __expf(-10.0f * INV_T - m_);
        loss[row] = m_ + __logf(tot) - lp * INV_T;
    }
}

// ---------------- host ----------------
extern "C" void kernel_launch(void* const* d_in, const int* in_sizes, int n_in,
                              void* d_out, int out_size, void* d_ws, size_t ws_size,
                              hipStream_t stream) {
    const float* fq = (const float*)d_in[0];
    const float* fk = (const float*)d_in[1];
    float* out = (float*)d_out;

    char* ws = (char*)d_ws;
    u16* keys = (u16*)ws;                                  // 128 MiB
    u16* qb = (u16*)(ws + (size_t)NROW * NROW * 2);        // 4 MiB
    u16* kb = qb + (size_t)NROW * NDIM;                    // 4 MiB

    cvt_bf16<<<4096, 256, 0, stream>>>(fq, fk, qb, kb);
    gemm_keys<<<dim3(NROW / 128, NROW / 128), 512, 0, stream>>>(qb, kb, keys);
    rank_lse<<<NROW / 2, 128, 0, stream>>>(keys, fq, fk, out);
}

// Round 16
// 119.613 us; speedup vs baseline: 2.4048x; 1.0257x over previous
//
#include <hip/hip_runtime.h>
#include <hip/hip_bf16.h>

#define NROW 8192
#define NDIM 256
#define INV_T (1.0f / 0.07f)
#define K_BOT 819      // first selected descending rank
#define K_TOP 4095     // one past last selected rank
#define N_SEL 3276
#define N_UNSEL 4916   // 8192 - N_SEL (includes diagonal at -10)

typedef unsigned int u32;
typedef unsigned short u16;
typedef short s16;
typedef unsigned long long u64;
typedef __bf16 bf16_t;
typedef s16 s16x8 __attribute__((ext_vector_type(8)));
typedef float f32x4 __attribute__((ext_vector_type(4)));

__device__ __forceinline__ u16 bfbits(float f) {
    return __builtin_bit_cast(u16, (bf16_t)f);   // RNE f32->bf16, raw bits
}
// order-preserving bf16-bits -> u16 key (bigger float <=> bigger key)
__device__ __forceinline__ u16 map16(u16 b) {
    return (b & 0x8000u) ? (u16)~b : (u16)(b | 0x8000u);
}
__device__ __forceinline__ float unmap16(u32 m) {
    u16 b = (m & 0x8000u) ? (u16)(m & 0x7FFFu) : (u16)~(u16)m;
    return __uint_as_float(((u32)b) << 16);
}

__device__ __forceinline__ void gload16(const void* g, void* l) {
    __builtin_amdgcn_global_load_lds(
        (const __attribute__((address_space(1))) u32*)g,
        (__attribute__((address_space(3))) u32*)l, 16, 0, 0);
}

// ---------------- fp32 -> bf16 (both inputs, one launch) ----------------
__global__ __launch_bounds__(256) void cvt_bf16(const float* __restrict__ in0,
                                                const float* __restrict__ in1,
                                                u16* __restrict__ out0,
                                                u16* __restrict__ out1) {
    int b = blockIdx.x;
    const float* in = (b < 2048) ? in0 : in1;
    u16* out = (b < 2048) ? out0 : out1;
    int i = ((b & 2047) * 256 + threadIdx.x) * 4;
    float4 v = *(const float4*)(in + i);
    ushort4 o;
    o.x = bfbits(v.x); o.y = bfbits(v.y); o.z = bfbits(v.z); o.w = bfbits(v.w);
    *(ushort4*)(out + i) = o;
}

// ---------------- GEMM: keys = map16(bf16(Q @ K^T)) ----------------
// 128x128 tile, BK=64, 8 waves (512 thr), wave tile 64x32 (acc 32 regs).
// Proven round-14 form. No min-waves launch_bounds (round-13 spill lesson).
__global__ __launch_bounds__(512) void gemm_keys(const u16* __restrict__ Qb,
                                                 const u16* __restrict__ Kb,
                                                 u16* __restrict__ Cp) {
    constexpr int BK = 64;
    __shared__ __align__(16) char smem[128 * 132 * 2];   // 33792 B (union)
    u16* sA = (u16*)smem;                    // [128][64] bf16 (16 KB)
    u16* sB = (u16*)(smem + 128 * BK * 2);   // [128][64] (16 KB)
    u16* sC = (u16*)smem;                    // [128][132] epilogue transpose

    const int tid  = threadIdx.x;
    const int lane = tid & 63;
    const int wid  = tid >> 6;               // 0..7
    const int wr = wid & 1;                  // row half   (64 rows)
    const int wc = wid >> 1;                 // col quarter (32 cols)
    const int bm = blockIdx.y * 128;
    const int bn = blockIdx.x * 128;
    const int kg = lane >> 4;
    const int fr = lane & 15;

    // staging: segment = 8 rows x 128B; lane l -> row seg*8 + (l>>3),
    // LDS chunk jp = l&7 holds source chunk j = jp ^ (row&7).
    const int srr = lane >> 3;
    const int srj = (lane & 7) ^ srr;

    f32x4 acc[4][2] = {};

    for (int k0 = 0; k0 < NDIM; k0 += BK) {
        __syncthreads();
#pragma unroll
        for (int s = 0; s < 2; ++s) {
            int seg = wid * 2 + s;               // 0..15
            int row = seg * 8 + srr;
            gload16(Qb + (size_t)(bm + row) * NDIM + k0 + srj * 8, &sA[seg * 512]);
            gload16(Kb + (size_t)(bn + row) * NDIM + k0 + srj * 8, &sB[seg * 512]);
        }
        __syncthreads();

#pragma unroll
        for (int kk = 0; kk < 2; ++kk) {
            s16x8 af[4], bfv[2];
            const int jp = (kk * 4 + kg) ^ (fr & 7);   // row&7 == fr&7 below
#pragma unroll
            for (int m = 0; m < 4; ++m) {
                int row = wr * 64 + m * 16 + fr;
                af[m] = *(const s16x8*)(&sA[row * BK + jp * 8]);
            }
#pragma unroll
            for (int n = 0; n < 2; ++n) {
                int row = wc * 32 + n * 16 + fr;
                bfv[n] = *(const s16x8*)(&sB[row * BK + jp * 8]);
            }
#pragma unroll
            for (int m = 0; m < 4; ++m)
#pragma unroll
                for (int n = 0; n < 2; ++n)
                    acc[m][n] = __builtin_amdgcn_mfma_f32_16x16x32_bf16(
                        af[m], bfv[n], acc[m][n], 0, 0, 0);
        }
    }

    __syncthreads();   // done reading sA/sB; reuse LDS as sC
#pragma unroll
    for (int m = 0; m < 4; ++m)
#pragma unroll
        for (int n = 0; n < 2; ++n)
#pragma unroll
            for (int jj = 0; jj < 4; ++jj) {
                int r = wr * 64 + m * 16 + kg * 4 + jj;   // C/D: row=(lane>>4)*4+reg
                int c = wc * 32 + n * 16 + fr;            //      col=lane&15
                sC[r * 132 + c] = map16(bfbits(acc[m][n][jj]));
            }
    __syncthreads();
    if (bm == bn) {
        if (tid < 128) sC[tid * 132 + tid] = 0;   // diagonal sentinel (unique min)
        __syncthreads();
    }
#pragma unroll
    for (int it = 0; it < 4; ++it) {
        int idx = it * 512 + tid;                 // 0..2047 16B chunks
        int row = idx >> 4, col8 = (idx & 15) * 8;
        *(uint4*)(&Cp[(size_t)(bm + row) * NROW + bn + col8]) =
            *(const uint4*)(&sC[row * 132 + col8]);
    }
}

// ---------------- rank select + LSE: 1 wave/row, 0 barriers, 2 sweeps -----
// resolve rank `rem` within a 128-key sub-hist (packed u16 counts, 64 words)
__device__ __forceinline__ void resolve_slot(const u32* sub, int slot, u32 rem,
                                             int lane, u32* idxOut, u32* gtOut) {
    u32 word = sub[slot * 64 + lane];
    u32 c0 = word & 0xFFFFu, c1 = word >> 16;     // idx 2*lane, 2*lane+1
    u32 s0 = c0 + c1, suf = s0;
#pragma unroll
    for (int o = 1; o < 64; o <<= 1) {
        u32 v = __shfl_down(suf, o);
        if (lane + o < 64) suf += v;
    }
    u32 TexL = suf - s0;                  // counts in higher lanes
    u32 f = 0, pk = 0;
    u32 ab0 = TexL + c1;                  // keys above idx 2*lane
    if (rem >= ab0 && rem < ab0 + c0) { f = 1; pk = ((u32)(lane * 2) << 16) | ab0; }
    if (rem >= TexL && rem < TexL + c1) { f = 1; pk = ((u32)(lane * 2 + 1) << 16) | TexL; }
    u64 mm = __ballot(f != 0);
    pk = __shfl(pk, (int)(__ffsll((unsigned long long)mm) - 1));
    *idxOut = pk >> 16;
    *gtOut = pk & 0xFFFFu;
}

// 128-thread blocks (2 independent waves). S1 hist: 4 interleaved copies
// (lane&3) of u16-packed counts — bin b -> word c*264 + (b&255), half b>>8.
// Halves same-address atomic serialization vs 2-copy u32 (round-15: DS pipe
// was the shared-resource limiter; conflicts 10.6M).
__global__ __launch_bounds__(128, 8) void rank_lse(const u16* __restrict__ Cp,
                                                   const float* __restrict__ fq,
                                                   const float* __restrict__ fk,
                                                   float* __restrict__ loss) {
    __shared__ u32 lds_s[2][1056];        // 8448 B/block; per-wave private
    const int t = threadIdx.x;
    const int w = t >> 6;
    const int lane = t & 63;
    const int row = blockIdx.x * 2 + w;

    u32* W   = lds_s[w];                  // 4 copies x 264 words (u16-packed)
    u32* sub = W;                          // [0,512) S2 sub-hists (alias, hist dead)

    const uint4* rp = (const uint4*)(Cp + (size_t)row * NROW);

    // zero all 1056 hist words
    {
        const uint4 z = make_uint4(0, 0, 0, 0);
#pragma unroll
        for (int i = 0; i < 4; ++i) *(uint4*)&W[i * 256 + lane * 4] = z;
        if (lane < 8) *(uint4*)&W[1024 + lane * 4] = z;
    }

    // exact fp32 l_pos
    float lp;
    {
        float4 q4 = *(const float4*)(fq + (size_t)row * NDIM + lane * 4);
        float4 k4 = *(const float4*)(fk + (size_t)row * NDIM + lane * 4);
        float p = q4.x * k4.x + q4.y * k4.y + q4.z * k4.z + q4.w * k4.w;
#pragma unroll
        for (int o = 32; o; o >>= 1) p += __shfl_down(p, o);
        lp = __shfl(p, 0);
    }

    // ---- S1: 512-bin hist (key>>7), 4 interleaved u16-packed copies ----
    u32* const hc = &W[(lane & 3) * 264];
#pragma unroll 4
    for (int i = 0; i < 16; ++i) {
        uint4 v = rp[i * 64 + lane];
        u32 vv[4] = { v.x, v.y, v.z, v.w };
#pragma unroll
        for (int q = 0; q < 4; ++q) {
            u32 b0 = (vv[q] >> 7) & 0x1FFu;
            u32 b1 = vv[q] >> 23;
            atomicAdd(&hc[b0 & 255u], 1u << ((b0 & 0x100u) >> 4));
            atomicAdd(&hc[b1 & 255u], 1u << ((b1 & 0x100u) >> 4));
        }
    }

    // ---- merge copies + suffix scan (8 bins/lane over 512) ----
    u32 h[8], Wa[8];
    {
        u32 hx[8] = {0, 0, 0, 0, 0, 0, 0, 0};
        const int wbase = (lane & 31) * 8;
        const u32 hsh = (u32)(lane >> 5) * 16;   // low/high half select
#pragma unroll
        for (int c = 0; c < 4; ++c) {
            uint4 w0 = *(const uint4*)&W[c * 264 + wbase];
            uint4 w1 = *(const uint4*)&W[c * 264 + wbase + 4];
            u32 ws[8] = { w0.x, w0.y, w0.z, w0.w, w1.x, w1.y, w1.z, w1.w };
#pragma unroll
            for (int j = 0; j < 8; ++j) hx[j] += (ws[j] >> hsh) & 0xFFFFu;
        }
#pragma unroll
        for (int j = 0; j < 8; ++j) h[j] = hx[j];
    }
    Wa[7] = 0;
#pragma unroll
    for (int j = 6; j >= 0; --j) Wa[j] = Wa[j + 1] + h[j + 1];
    u32 P = Wa[0] + h[0];
    u32 s = P;
#pragma unroll
    for (int o = 1; o < 64; o <<= 1) {
        u32 vv = __shfl_down(s, o);
        if (lane + o < 64) s += vv;
    }
    const u32 Tex = s - P;

    u32 fA = 0, pkA = 0, fB = 0, pkB = 0;
#pragma unroll
    for (int j = 0; j < 8; ++j) {
        u32 T = Tex + Wa[j];
        u32 e = T + h[j];
        if ((u32)K_BOT >= T && (u32)K_BOT < e)
            { fA = 1; pkA = ((u32)(lane * 8 + j) << 13) | ((u32)K_BOT - T); }
        if ((u32)(K_TOP - 1) >= T && (u32)(K_TOP - 1) < e)
            { fB = 1; pkB = ((u32)(lane * 8 + j) << 13) | ((u32)(K_TOP - 1) - T); }
    }
    {
        u64 mA = __ballot(fA != 0);
        pkA = __shfl(pkA, (int)(__ffsll((unsigned long long)mA) - 1));
        u64 mB = __ballot(fB != 0);
        pkB = __shfl(pkB, (int)(__ffsll((unsigned long long)mB) - 1));
    }
    const u32 binA = pkA >> 13, remA = pkA & 8191u;
    const u32 binB = pkB >> 13, remB = pkB & 8191u;
    const u32 TA = (u32)K_BOT - remA;
    const u32 TB = (u32)(K_TOP - 1) - remB;

    // ---- slot assignment (pure arithmetic) ----
    const float edgeA = unmap16(binA << 7);
    int lo2, topSlots;
    bool fb = false;
    if (edgeA > -1e37f && edgeA < 1e37f) {
        float vt = edgeA - 2.8f;
        int vtBin = (int)((u32)map16(bfbits(vt)) >> 7);
        int binLoSafe = vtBin - 1; if (binLoSafe < 0) binLoSafe = 0;
        int m = (binLoSafe < (int)binA) ? binLoSafe : (int)binA;
        lo2 = ((int)binB + 1 > m) ? (int)binB + 1 : m;
        topSlots = ((int)binA >= lo2) ? ((int)binA - lo2 + 1) : 0;
        if (topSlots + 1 > 8) fb = true;
    } else {
        fb = true;
    }
    if (fb) {                       // fallback: slots only for binB, binA
        lo2 = (int)binA;
        topSlots = ((int)binA > (int)binB) ? 1 : 0;
    }
    const int nslot = topSlots + 1;
    const int sA = topSlots;        // slot of binA (0 when binA==binB)

    // ---- zero sub region, then S2: sub-hist sweep (packed u16 counts) ----
    {
        const uint4 z = make_uint4(0, 0, 0, 0);
#pragma unroll
        for (int i = 0; i < 2; ++i) *(uint4*)&sub[i * 256 + lane * 4] = z;
    }
#pragma unroll 4
    for (int i = 0; i < 16; ++i) {
        uint4 v = rp[i * 64 + lane];
        u32 vv[4] = { v.x, v.y, v.z, v.w };
#pragma unroll
        for (int q = 0; q < 4; ++q) {
#pragma unroll
            for (int hh = 0; hh < 2; ++hh) {
                u32 key = hh ? (vv[q] >> 16) : (vv[q] & 0xFFFFu);
                u32 b = key >> 7;
                int sl = (b == binB) ? 0
                       : (((u32)((int)b - lo2) < (u32)topSlots) ? ((int)b - lo2 + 1) : -1);
                if (sl >= 0)
                    atomicAdd(&sub[sl * 64 + ((key & 127u) >> 1)],
                              (key & 1u) ? 0x10000u : 1u);
            }
        }
    }

    // ---- resolve exact boundary keys + tie counts ----
    u32 idxA, gtA, idxB, gtB;
    resolve_slot(sub, sA, remA, lane, &idxA, &gtA);
    resolve_slot(sub, 0,  remB, lane, &idxB, &gtB);
    const u32 ua = (binA << 7) | idxA;
    const u32 ub = (binB << 7) | idxB;
    const u32 Ga = TA + gtA;
    const u32 Gb = TB + gtB;
    u32 Ea;
    {
        u32 wv = sub[sA * 64 + (idxA >> 1)];
        Ea = (idxA & 1u) ? (wv >> 16) : (wv & 0xFFFFu);
    }

    const float a  = unmap16(ua);
    const float m_ = fmaxf(fmaxf(lp, a), -10.0f) * INV_T;   // exact max

    // ---- window sum ----
    float sm = 0.f;
    if (!fb) {
        for (int ss = 0; ss < nslot; ++ss) {          // wave-uniform
            u32 bs = (ss == 0) ? binB : (u32)(lo2 + ss - 1);
            u32 wv = sub[ss * 64 + lane];
            u32 c0 = wv & 0xFFFFu, c1 = wv >> 16;
            u32 k0 = (bs << 7) | (u32)(lane * 2);
            u32 k1 = k0 | 1u;
            if (c0 && k0 > ub && k0 < ua)
                sm += (float)c0 * __expf(unmap16(k0) * INV_T - m_);
            if (c1 && k1 > ub && k1 < ua)
                sm += (float)c1 * __expf(unmap16(k1) * INV_T - m_);
        }
    } else if (ua != ub) {
        // rare fallback: one extra full sweep with exact m_
        const u32 lo1 = ub + 1u, span = ua - ub - 1u;
#pragma unroll 4
        for (int i = 0; i < 16; ++i) {
            uint4 v = rp[i * 64 + lane];
            u32 vv[4] = { v.x, v.y, v.z, v.w };
#pragma unroll
            for (int q = 0; q < 4; ++q) {
#pragma unroll
                for (int hh = 0; hh < 2; ++hh) {
                    u32 key = hh ? (vv[q] >> 16) : (vv[q] & 0xFFFFu);
                    bool in = (key - lo1) < span;
                    float e = __expf(unmap16(key) * INV_T - m_);
                    sm += in ? e : 0.f;
                }
            }
        }
    }
#pragma unroll
    for (int o = 32; o; o >>= 1) sm += __shfl_down(sm, o);

    if (lane == 0) {
        float bv = unmap16(ub);
        float expA = __expf(a * INV_T - m_);
        float tot;
        if (ua == ub) {
            tot = (float)N_SEL * expA;
        } else {
            float expB = __expf(bv * INV_T - m_);
            tot = sm + (float)(int)(Ga + Ea - (u32)K_BOT) * expA
                     + (float)(int)((u32)K_TOP - Gb) * expB;
        }
        tot += __expf(lp * INV_T - m_) + (float)N_UNSEL * __expf(-10.0f * INV_T - m_);
        loss[row] = m_ + __logf(tot) - lp * INV_T;
    }
}

// ---------------- host ----------------
extern "C" void kernel_launch(void* const* d_in, const int* in_sizes, int n_in,
                              void* d_out, int out_size, void* d_ws, size_t ws_size,
                              hipStream_t stream) {
    const float* fq = (const float*)d_in[0];
    const float* fk = (const float*)d_in[1];
    float* out = (float*)d_out;

    char* ws = (char*)d_ws;
    u16* keys = (u16*)ws;                                  // 128 MiB
    u16* qb = (u16*)(ws + (size_t)NROW * NROW * 2);        // 4 MiB
    u16* kb = qb + (size_t)NROW * NDIM;                    // 4 MiB

    cvt_bf16<<<4096, 256, 0, stream>>>(fq, fk, qb, kb);
    gemm_keys<<<dim3(NROW / 128, NROW / 128), 512, 0, stream>>>(qb, kb, keys);
    rank_lse<<<NROW / 2, 128, 0, stream>>>(keys, fq, fk, out);
}